// Round 16
// baseline (6788.200 us; speedup 1.0000x reference)
//
#include <hip/hip_runtime.h>
#include <math.h>

#define VOCAB 50000
#define EMB 256
#define HID 512
#define G4 2048   // 4*HID
#define KTAGS 20
#define START_TAG 18
#define END_TAG 19
#define BB 32
#define TT 256
#define NEGV -10000.0f
#define HSROW 644   // 640 phys floats per row + 4 skew
#define XSROW 264   // 256 + 8 skew

__device__ __forceinline__ float sigmoidf_(float x) { return 1.0f / (1.0f + expf(-x)); }

// ---------------------------------------------------------------------------
// K2: persistent batched LSTM, dual-dir merged + fused input GEMM,
//     SINGLE-BARRIER step protocol:
//   - arrivals are PER-WAVE (after that wave's own sc1 gate-store drain):
//     counter line target = t*64 (8 slices x 8 waves per line)
//   - ALL waves poll; detection implies own-WG waves finished prior dot
//     (they arrived), so hs/xs overwrite is safe with NO release barrier
//   - only barrier left: stage->dot LDS visibility syncthreads
// ---------------------------------------------------------------------------
__global__ __launch_bounds__(512, 1) void k_lstm_persist(
    const int* __restrict__ lengths,
    const int* __restrict__ sentence,  // [32][256]
    const float* __restrict__ emb,     // [VOCAB][256]
    const float* __restrict__ Wf_hh, const float* __restrict__ Wb_hh,
    const float* __restrict__ Wf_ih, const float* __restrict__ Wb_ih,
    const float* __restrict__ bf_ih, const float* __restrict__ bf_hh,
    const float* __restrict__ bb_ih, const float* __restrict__ bb_hh,
    float* __restrict__ hping,         // [2 parity][2 dir][32][512]
    unsigned* __restrict__ bar,        // [8 cohorts][8 lines x 16 uints]
    float* __restrict__ hbuf)          // [2][32][256][512]
{
    const int wg = blockIdx.x;             // 0..255
    const int slice = wg >> 2;             // unit slice 0..63
    const int grp = wg & 3;                // sorted batch group 0..3
    const int tid = threadIdx.x;
    const int wave = tid >> 6;             // 0..7 = local unit
    const int lane = tid & 63;             // k-slice
    const int u_glob = slice * 8 + wave;   // 0..511

    float4 wF[4][2], wB[4][2];
    #pragma unroll
    for (int c = 0; c < 4; c++) {
        const float4* wr = (const float4*)(Wf_hh + (size_t)(c * HID + u_glob) * HID + lane * 8);
        wF[c][0] = wr[0]; wF[c][1] = wr[1];
        const float4* wr2 = (const float4*)(Wb_hh + (size_t)(c * HID + u_glob) * HID + lane * 8);
        wB[c][0] = wr2[0]; wB[c][1] = wr2[1];
    }
    float4 iF[4], iB[4];
    #pragma unroll
    for (int c = 0; c < 4; c++) {
        iF[c] = *(const float4*)(Wf_ih + (size_t)(c * HID + u_glob) * EMB + lane * 4);
        iB[c] = *(const float4*)(Wb_ih + (size_t)(c * HID + u_glob) * EMB + lane * 4);
    }
    float bFc[4], bBc[4];
    #pragma unroll
    for (int c = 0; c < 4; c++) {
        bFc[c] = bf_ih[c * HID + u_glob] + bf_hh[c * HID + u_glob];
        bBc[c] = bb_ih[c * HID + u_glob] + bb_hh[c * HID + u_glob];
    }

    __shared__ float hs[16 * HSROW];       // rows 0-7: F h, 8-15: B h
    __shared__ float xs[16 * XSROW];       // rows 0-7: F x, 8-15: B x
    __shared__ float zw[16 * 132];         // [dir*8+wave][gate*33 + j]
    __shared__ int stok[8][TT];
    __shared__ int lens_raw[32];
    __shared__ int order_s[32];
    __shared__ int lens_s[32];
    __shared__ int nbt_s[TT];

    if (tid < 32) lens_raw[tid] = lengths[tid];
    __syncthreads();
    if (tid < 32) {
        int me = lens_raw[tid], rank = 0;
        #pragma unroll 4
        for (int o = 0; o < 32; o++) {
            int lo = lens_raw[o];
            rank += (lo > me || (lo == me && o < tid)) ? 1 : 0;
        }
        order_s[rank] = tid;
        lens_s[rank] = me;
    }
    if (tid >= 256) {
        int t = tid - 256, c = 0;
        #pragma unroll 4
        for (int b = 0; b < 32; b++) c += (lens_raw[b] > t) ? 1 : 0;
        nbt_s[t] = c;
    }
    __syncthreads();
    for (int i = tid; i < 8 * TT; i += 512) {
        int j = i >> 8, c = i & 255;
        stok[j][c] = sentence[order_s[grp * 8 + j] * TT + c];
    }
    __syncthreads();

    const int tlimit = lens_s[grp * 8];

    const int gj = lane & 7;
    const int g_act = (lane < 8);
    const int p_sort = grp * 8 + gj;
    const int mylen = lens_s[p_sort];
    const int mybat = order_s[p_sort];
    float* houtF = hbuf + (size_t)mybat * TT * HID + u_glob;
    float* houtB = hbuf + (size_t)(BB + mybat) * TT * HID + u_glob;
    float* hpF = hping + (size_t)mybat * HID + u_glob;
    float* hpB = hping + (size_t)(BB + mybat) * HID + u_glob;

    const int kq = tid & 127;
    const int rA = tid >> 7;
    const int wbBase = 4 * kq + 4 * (kq >> 2);
    const int sb_lo = order_s[grp * 8 + rA];
    const int sb_hi = order_s[grp * 8 + rA + 4];

    const int xrow = tid >> 5;
    const int xpart = tid & 31;
    const int xjrow = xrow & 7;
    const int xlen = lens_s[grp * 8 + xjrow];
    const bool xisB = xrow >= 8;
    float* xdst = &xs[xrow * XSROW + xpart * 8];

    const int rdoff = 8 * lane + 4 * (lane >> 1);

    float cF = 0.f, cB = 0.f;
    unsigned* barF = bar + grp * 128;
    unsigned* barB = bar + (4 + grp) * 128;
    const int arr_line = (slice & 7) * 16;

#define DOTRED(WREG, WIH, ROWOFF, ZOFF)                                        \
    for (int j = 0; j < jmax; j++) {                                           \
        const float* hb = &hs[((ROWOFF) + j) * HSROW + rdoff];                 \
        float4 h0 = *(const float4*)(hb);                                      \
        float4 h1 = *(const float4*)(hb + 4);                                  \
        float4 xv = *(const float4*)&xs[((ROWOFF) + j) * XSROW + lane * 4];    \
        float a0 = 0.f, a1 = 0.f, a2 = 0.f, a3 = 0.f;                          \
        a0 = fmaf(WREG[0][0].x, h0.x, a0); a0 = fmaf(WREG[0][0].y, h0.y, a0);  \
        a0 = fmaf(WREG[0][0].z, h0.z, a0); a0 = fmaf(WREG[0][0].w, h0.w, a0);  \
        a0 = fmaf(WREG[0][1].x, h1.x, a0); a0 = fmaf(WREG[0][1].y, h1.y, a0);  \
        a0 = fmaf(WREG[0][1].z, h1.z, a0); a0 = fmaf(WREG[0][1].w, h1.w, a0);  \
        a0 = fmaf(WIH[0].x, xv.x, a0);     a0 = fmaf(WIH[0].y, xv.y, a0);      \
        a0 = fmaf(WIH[0].z, xv.z, a0);     a0 = fmaf(WIH[0].w, xv.w, a0);      \
        a1 = fmaf(WREG[1][0].x, h0.x, a1); a1 = fmaf(WREG[1][0].y, h0.y, a1);  \
        a1 = fmaf(WREG[1][0].z, h0.z, a1); a1 = fmaf(WREG[1][0].w, h0.w, a1);  \
        a1 = fmaf(WREG[1][1].x, h1.x, a1); a1 = fmaf(WREG[1][1].y, h1.y, a1);  \
        a1 = fmaf(WREG[1][1].z, h1.z, a1); a1 = fmaf(WREG[1][1].w, h1.w, a1);  \
        a1 = fmaf(WIH[1].x, xv.x, a1);     a1 = fmaf(WIH[1].y, xv.y, a1);      \
        a1 = fmaf(WIH[1].z, xv.z, a1);     a1 = fmaf(WIH[1].w, xv.w, a1);      \
        a2 = fmaf(WREG[2][0].x, h0.x, a2); a2 = fmaf(WREG[2][0].y, h0.y, a2);  \
        a2 = fmaf(WREG[2][0].z, h0.z, a2); a2 = fmaf(WREG[2][0].w, h0.w, a2);  \
        a2 = fmaf(WREG[2][1].x, h1.x, a2); a2 = fmaf(WREG[2][1].y, h1.y, a2);  \
        a2 = fmaf(WREG[2][1].z, h1.z, a2); a2 = fmaf(WREG[2][1].w, h1.w, a2);  \
        a2 = fmaf(WIH[2].x, xv.x, a2);     a2 = fmaf(WIH[2].y, xv.y, a2);      \
        a2 = fmaf(WIH[2].z, xv.z, a2);     a2 = fmaf(WIH[2].w, xv.w, a2);      \
        a3 = fmaf(WREG[3][0].x, h0.x, a3); a3 = fmaf(WREG[3][0].y, h0.y, a3);  \
        a3 = fmaf(WREG[3][0].z, h0.z, a3); a3 = fmaf(WREG[3][0].w, h0.w, a3);  \
        a3 = fmaf(WREG[3][1].x, h1.x, a3); a3 = fmaf(WREG[3][1].y, h1.y, a3);  \
        a3 = fmaf(WREG[3][1].z, h1.z, a3); a3 = fmaf(WREG[3][1].w, h1.w, a3);  \
        a3 = fmaf(WIH[3].x, xv.x, a3);     a3 = fmaf(WIH[3].y, xv.y, a3);      \
        a3 = fmaf(WIH[3].z, xv.z, a3);     a3 = fmaf(WIH[3].w, xv.w, a3);      \
        bool lo32 = (lane & 32) == 0;                                          \
        float tA = __shfl_xor(lo32 ? a2 : a0, 32);                             \
        float tB = __shfl_xor(lo32 ? a3 : a1, 32);                             \
        float rAq = (lo32 ? a0 : a2) + tA;                                     \
        float rBq = (lo32 ? a1 : a3) + tB;                                     \
        bool lo16 = (lane & 16) == 0;                                          \
        float tC = __shfl_xor(lo16 ? rBq : rAq, 16);                           \
        float r  = (lo16 ? rAq : rBq) + tC;                                    \
        r += __shfl_xor(r, 8);                                                 \
        r += __shfl_xor(r, 4);                                                 \
        r += __shfl_xor(r, 2);                                                 \
        r += __shfl_xor(r, 1);                                                 \
        if ((lane & 15) == 0)                                                  \
            zw[((ZOFF) + wave) * 132 + (lane >> 4) * 33 + j] = r;              \
    }

    for (int t = 0; t < tlimit; t++) {
        const int nbt = nbt_s[t];
        const int jmax = min(max(nbt - grp * 8, 0), 8);
        const int act = g_act && (t < mylen);
        const int pred_lo = (grp * 8 + rA < nbt);
        const int pred_hi = (grp * 8 + rA + 4 < nbt);

        // ---- prefetch x rows (barrier-independent) ----
        int posx = xisB ? ((t < xlen) ? xlen - 1 - t : t) : t;
        const float* xr = emb + (size_t)stok[xjrow][posx] * EMB + xpart * 8;
        float4 xa = *(const float4*)xr;
        float4 xb2 = *(const float4*)(xr + 4);

        // ---- ALL-WAVE poll: detection implies own-WG waves done with t-1 ----
        if (t > 0) {
            const unsigned tgt = (unsigned)t * 64u;   // 8 slices x 8 waves per line
            const unsigned* cp = (lane < 8) ? (barF + lane * 16)
                               : (lane < 16) ? (barB + (lane - 8) * 16)
                               : barF;
            bool mydone = (lane >= 16);
            while (true) {
                if (!mydone)
                    mydone = __hip_atomic_load(cp, __ATOMIC_RELAXED,
                                               __HIP_MEMORY_SCOPE_AGENT) >= tgt;
                if (__ballot(mydone) == ~0ull) break;
                __builtin_amdgcn_s_sleep(1);
            }
        }

        // ---- stage h(t) for BOTH dirs: 4 sc1 dwordx4 loads, one vmcnt ----
        {
            const char* baseF = (const char*)hping + (size_t)((t & 1) * 2) * BB * HID * 4;
            const char* baseB = baseF + (size_t)BB * HID * 4;
            const char* fb = baseF + (tid & 63) * 16;
            const char* a0 = pred_lo ? baseF + sb_lo * 2048 + kq * 16 : fb;
            const char* a1 = pred_hi ? baseF + sb_hi * 2048 + kq * 16 : fb;
            const char* a2 = pred_lo ? baseB + sb_lo * 2048 + kq * 16 : fb;
            const char* a3 = pred_hi ? baseB + sb_hi * 2048 + kq * 16 : fb;
            float4 u0, u1, u2, u3;
            asm volatile(
                "global_load_dwordx4 %0, %4, off sc0 sc1\n\t"
                "global_load_dwordx4 %1, %5, off sc0 sc1\n\t"
                "global_load_dwordx4 %2, %6, off sc0 sc1\n\t"
                "global_load_dwordx4 %3, %7, off sc0 sc1\n\t"
                "s_waitcnt vmcnt(0)"
                : "=&v"(u0), "=&v"(u1), "=&v"(u2), "=&v"(u3)
                : "v"(a0), "v"(a1), "v"(a2), "v"(a3)
                : "memory");
            *(float4*)&hs[(rA     ) * HSROW + wbBase] = u0;
            *(float4*)&hs[(rA +  4) * HSROW + wbBase] = u1;
            *(float4*)&hs[(rA +  8) * HSROW + wbBase] = u2;
            *(float4*)&hs[(rA + 12) * HSROW + wbBase] = u3;
            *(float4*)xdst = xa;
            *(float4*)(xdst + 4) = xb2;
        }
        __syncthreads();                       // the ONLY barrier per step

        // ---- dots: F then B (Whh.h + Wih.x fused) ----
        DOTRED(wF, iF, 0, 0);
        DOTRED(wB, iB, 8, 8);

        // ---- gates: both dirs; exchange (hping) stores ----
        float hnF = 0.f, hnB = 0.f;
        if (act) {
            {
                float iv = zw[wave * 132 +  0 + gj] + bFc[0];
                float fv = zw[wave * 132 + 33 + gj] + bFc[1];
                float gv = zw[wave * 132 + 66 + gj] + bFc[2];
                float ov = zw[wave * 132 + 99 + gj] + bFc[3];
                float cn = sigmoidf_(fv) * cF + sigmoidf_(iv) * tanhf(gv);
                hnF = sigmoidf_(ov) * tanhf(cn);
                cF = cn;
                __hip_atomic_store(hpF + (size_t)(((t + 1) & 1) * 2) * BB * HID,
                                   hnF, __ATOMIC_RELAXED, __HIP_MEMORY_SCOPE_AGENT);
            }
            {
                float iv = zw[(8 + wave) * 132 +  0 + gj] + bBc[0];
                float fv = zw[(8 + wave) * 132 + 33 + gj] + bBc[1];
                float gv = zw[(8 + wave) * 132 + 66 + gj] + bBc[2];
                float ov = zw[(8 + wave) * 132 + 99 + gj] + bBc[3];
                float cn = sigmoidf_(fv) * cB + sigmoidf_(iv) * tanhf(gv);
                hnB = sigmoidf_(ov) * tanhf(cn);
                cB = cn;
                __hip_atomic_store(hpB + (size_t)(((t + 1) & 1) * 2) * BB * HID,
                                   hnB, __ATOMIC_RELAXED, __HIP_MEMORY_SCOPE_AGENT);
            }
        }

        // ---- per-wave self-drain + per-wave arrive (no WG barrier) ----
        if (t < tlimit - 1) {
            asm volatile("s_waitcnt vmcnt(0)" ::: "memory");  // this wave's stores visible
            if (lane == 0)
                __hip_atomic_fetch_add(barF + arr_line, 1u,
                                       __ATOMIC_RELAXED, __HIP_MEMORY_SCOPE_AGENT);
            if (lane == 1)
                __hip_atomic_fetch_add(barB + arr_line, 1u,
                                       __ATOMIC_RELAXED, __HIP_MEMORY_SCOPE_AGENT);
        }

        // ---- history stores after arrive (latency hides in next poll) ----
        if (act) {
            houtF[(size_t)t * HID] = hnF;
            houtB[(size_t)t * HID] = hnB;
        }
    }
#undef DOTRED
}

// ---------------------------------------------------------------------------
// K3: feats — one wave per (b,t), all 64 lanes, LDS transpose-reduce.
// ---------------------------------------------------------------------------
__global__ __launch_bounds__(256) void k_feats(
    const int* __restrict__ lengths,
    const float* __restrict__ hbuf,  // [2][B][T][512]
    const float* __restrict__ Wout,  // [20][1024]
    const float* __restrict__ bout,  // [20]
    float* __restrict__ feats)       // [B][T][20]
{
    const int w = threadIdx.x >> 6;
    const int lane = threadIdx.x & 63;
    const int idx = blockIdx.x * 4 + w;
    const int b = idx >> 8, t = idx & 255;
    const int len = lengths[b];

    __shared__ float red[4][64][21];

    float acc[KTAGS];
    bool active = (t < len);
    if (active) {
        const int ofs = lane * 16;
        const float* src = (ofs < HID)
            ? hbuf + ((size_t)b * TT + t) * HID + ofs
            : hbuf + ((size_t)(BB + b) * TT + (len - 1 - t)) * HID + (ofs - HID);
        float x[16];
        #pragma unroll
        for (int q = 0; q < 4; q++) {
            float4 v = *(const float4*)(src + 4 * q);
            x[4 * q] = v.x; x[4 * q + 1] = v.y; x[4 * q + 2] = v.z; x[4 * q + 3] = v.w;
        }
        #pragma unroll
        for (int k = 0; k < KTAGS; k++) {
            const float* wr = Wout + (size_t)k * (2 * HID) + ofs;
            float a = 0.f;
            #pragma unroll
            for (int q = 0; q < 4; q++) {
                float4 v = *(const float4*)(wr + 4 * q);
                a = fmaf(x[4 * q], v.x, a);
                a = fmaf(x[4 * q + 1], v.y, a);
                a = fmaf(x[4 * q + 2], v.z, a);
                a = fmaf(x[4 * q + 3], v.w, a);
            }
            acc[k] = a;
        }
    } else {
        #pragma unroll
        for (int k = 0; k < KTAGS; k++) acc[k] = 0.f;
    }
    #pragma unroll
    for (int k = 0; k < KTAGS; k++) red[w][lane][k] = acc[k];
    __syncthreads();

    if (active && lane < KTAGS) {
        float s = bout[lane];
        #pragma unroll 8
        for (int l = 0; l < 64; l++) s += red[w][l][lane];
        feats[(size_t)idx * KTAGS + lane] = s;
    }
}

// ---------------------------------------------------------------------------
// K4: Viterbi — LDS backpointers, double-buffered fv, feats prefetch.
// ---------------------------------------------------------------------------
__global__ __launch_bounds__(64) void k_viterbi(
    const int* __restrict__ lengths,
    const float* __restrict__ trans,  // [20][20]
    const float* __restrict__ feats,  // [B][T][20]
    float* __restrict__ out)          // [32 scores][32*257 path]
{
    const int b = blockIdx.x;
    const int len = lengths[b];
    const int tid = threadIdx.x;

    __shared__ float tr[KTAGS * KTAGS];
    __shared__ float fvb[2][KTAGS];
    __shared__ int   bp[TT][KTAGS];
    __shared__ float term[KTAGS];

    for (int i = tid; i < KTAGS * KTAGS; i += 64) tr[i] = trans[i];
    if (tid < KTAGS) fvb[0][tid] = (tid == START_TAG) ? 0.f : NEGV;
    __syncthreads();

    float ft = (tid < KTAGS) ? feats[((size_t)b * TT) * KTAGS + tid] : 0.f;
    for (int t = 0; t < len; t++) {
        float ftn = (tid < KTAGS && t + 1 < len)
                  ? feats[((size_t)b * TT + t + 1) * KTAGS + tid] : 0.f;
        if (tid < KTAGS) {
            const float* fvc = fvb[t & 1];
            float best = -1e30f; int bi = 0;
            #pragma unroll
            for (int p = 0; p < KTAGS; p++) {
                float s = fvc[p] + tr[tid * KTAGS + p];
                if (s > best) { best = s; bi = p; }
            }
            fvb[(t + 1) & 1][tid] = best + ft;
            bp[t][tid] = bi;
        }
        ft = ftn;
        __syncthreads();
    }

    if (tid < KTAGS) term[tid] = fvb[len & 1][tid] + tr[END_TAG * KTAGS + tid];
    __syncthreads();

    if (tid == 0) {
        int bt_ = 0; float best = term[0];
        for (int k = 1; k < KTAGS; k++)
            if (term[k] > best) { best = term[k]; bt_ = k; }
        out[b] = best;
        float* path = out + BB + (size_t)b * (TT + 1);
        path[TT] = (float)bt_;
        int cur = bt_;
        for (int t = TT - 1; t >= 0; t--) {
            int src = t - (TT - len);
            if (src >= 0) cur = bp[src][cur];
            else          cur = KTAGS;
            path[t] = (float)cur;
        }
    }
}

// ---------------------------------------------------------------------------
extern "C" void kernel_launch(void* const* d_in, const int* in_sizes, int n_in,
                              void* d_out, int out_size, void* d_ws, size_t ws_size,
                              hipStream_t stream) {
    const int*   sentence = (const int*)d_in[0];
    const int*   lengths  = (const int*)d_in[1];
    const float* emb      = (const float*)d_in[2];
    const float* Wf_ih    = (const float*)d_in[3];
    const float* Wf_hh    = (const float*)d_in[4];
    const float* bf_ih    = (const float*)d_in[5];
    const float* bf_hh    = (const float*)d_in[6];
    const float* Wb_ih    = (const float*)d_in[7];
    const float* Wb_hh    = (const float*)d_in[8];
    const float* bb_ih    = (const float*)d_in[9];
    const float* bb_hh    = (const float*)d_in[10];
    const float* Wout     = (const float*)d_in[11];
    const float* bout     = (const float*)d_in[12];
    const float* trans    = (const float*)d_in[13];
    float* out = (float*)d_out;

    // workspace layout
    float*    hping = (float*)d_ws;                            // 65536 floats (256KB)
    unsigned* bar   = (unsigned*)((char*)d_ws + 65536 * 4);    // 4KB (8 cohorts x 8 lines)
    float*    hbuf  = (float*)((char*)d_ws + 65536 * 4 + 4096);// 2*32*256*512 floats
    float*    feats = hbuf + (size_t)2 * BB * TT * HID;        // 32*256*20

    (void)hipMemsetAsync(d_ws, 0, 65536 * 4 + 4096, stream);

    hipLaunchKernelGGL(k_lstm_persist, dim3(256), dim3(512), 0, stream,
                       lengths, sentence, emb, Wf_hh, Wb_hh, Wf_ih, Wb_ih,
                       bf_ih, bf_hh, bb_ih, bb_hh, hping, bar, hbuf);
    hipLaunchKernelGGL(k_feats, dim3(BB * TT / 4), dim3(256), 0, stream,
                       lengths, hbuf, Wout, bout, feats);
    hipLaunchKernelGGL(k_viterbi, dim3(BB), dim3(64), 0, stream,
                       lengths, trans, feats, out);
}

// Round 17
// 2205.799 us; speedup vs baseline: 3.0774x; 3.0774x over previous
//
#include <hip/hip_runtime.h>
#include <math.h>

#define VOCAB 50000
#define EMB 256
#define HID 512
#define G4 2048   // 4*HID
#define KTAGS 20
#define START_TAG 18
#define END_TAG 19
#define BB 32
#define TT 256
#define NEGV -10000.0f
#define HSROW 644   // 640 phys floats per row + 4 skew
#define XSROW 264   // 256 + 8 skew

__device__ __forceinline__ float sigmoidf_(float x) { return 1.0f / (1.0f + expf(-x)); }

// ---------------------------------------------------------------------------
// K2: persistent batched LSTM, dual-dir merged phases + FUSED input GEMM.
//   256 WGs x 512 thr (1/CU). WG = (8-unit slice, 8-batch sorted group).
//   Per step: prefetch x=emb[tok] rows (barrier-independent), combined
//   cohort barrier wait (F lanes 0-7, B lanes 8-15), one staging round-trip
//   (8F+8B h-rows, sc1), dot = Whh.h + Wih.x (weights in VGPRs), gates,
//   drain, WG-level arrives (8/line — keeps same-line atomic RMW
//   serialization ~0.8us; per-wave arrives at 64/line cost +6.4us — r16),
//   THEN the hbuf history stores (out of the drain).
// ---------------------------------------------------------------------------
__global__ __launch_bounds__(512, 1) void k_lstm_persist(
    const int* __restrict__ lengths,
    const int* __restrict__ sentence,  // [32][256]
    const float* __restrict__ emb,     // [VOCAB][256]
    const float* __restrict__ Wf_hh, const float* __restrict__ Wb_hh,
    const float* __restrict__ Wf_ih, const float* __restrict__ Wb_ih,
    const float* __restrict__ bf_ih, const float* __restrict__ bf_hh,
    const float* __restrict__ bb_ih, const float* __restrict__ bb_hh,
    float* __restrict__ hping,         // [2 parity][2 dir][32][512]
    unsigned* __restrict__ bar,        // [8 cohorts][8 lines x 16 uints]
    float* __restrict__ hbuf)          // [2][32][256][512]
{
    const int wg = blockIdx.x;             // 0..255
    const int slice = wg >> 2;             // unit slice 0..63
    const int grp = wg & 3;                // sorted batch group 0..3
    const int tid = threadIdx.x;
    const int wave = tid >> 6;             // 0..7 = local unit
    const int lane = tid & 63;             // k-slice
    const int u_glob = slice * 8 + wave;   // 0..511

    // recurrent weights: 8 h-floats per lane per gate per dir
    float4 wF[4][2], wB[4][2];
    #pragma unroll
    for (int c = 0; c < 4; c++) {
        const float4* wr = (const float4*)(Wf_hh + (size_t)(c * HID + u_glob) * HID + lane * 8);
        wF[c][0] = wr[0]; wF[c][1] = wr[1];
        const float4* wr2 = (const float4*)(Wb_hh + (size_t)(c * HID + u_glob) * HID + lane * 8);
        wB[c][0] = wr2[0]; wB[c][1] = wr2[1];
    }
    // input weights: 4 x-floats per lane per gate per dir
    float4 iF[4], iB[4];
    #pragma unroll
    for (int c = 0; c < 4; c++) {
        iF[c] = *(const float4*)(Wf_ih + (size_t)(c * HID + u_glob) * EMB + lane * 4);
        iB[c] = *(const float4*)(Wb_ih + (size_t)(c * HID + u_glob) * EMB + lane * 4);
    }
    // biases for this wave's unit
    float bFc[4], bBc[4];
    #pragma unroll
    for (int c = 0; c < 4; c++) {
        bFc[c] = bf_ih[c * HID + u_glob] + bf_hh[c * HID + u_glob];
        bBc[c] = bb_ih[c * HID + u_glob] + bb_hh[c * HID + u_glob];
    }

    __shared__ float hs[16 * HSROW];       // rows 0-7: F h, 8-15: B h
    __shared__ float xs[16 * XSROW];       // rows 0-7: F x, 8-15: B x
    __shared__ float zw[16 * 132];         // [dir*8+wave][gate*33 + j]
    __shared__ int stok[8][TT];            // tokens for group's 8 sorted batches
    __shared__ int lens_raw[32];
    __shared__ int order_s[32];
    __shared__ int lens_s[32];
    __shared__ int nbt_s[TT];

    if (tid < 32) lens_raw[tid] = lengths[tid];
    __syncthreads();
    if (tid < 32) {
        int me = lens_raw[tid], rank = 0;
        #pragma unroll 4
        for (int o = 0; o < 32; o++) {
            int lo = lens_raw[o];
            rank += (lo > me || (lo == me && o < tid)) ? 1 : 0;
        }
        order_s[rank] = tid;
        lens_s[rank] = me;
    }
    if (tid >= 256) {
        int t = tid - 256, c = 0;
        #pragma unroll 4
        for (int b = 0; b < 32; b++) c += (lens_raw[b] > t) ? 1 : 0;
        nbt_s[t] = c;
    }
    __syncthreads();
    for (int i = tid; i < 8 * TT; i += 512) {
        int j = i >> 8, c = i & 255;
        stok[j][c] = sentence[order_s[grp * 8 + j] * TT + c];
    }
    __syncthreads();

    const int tlimit = lens_s[grp * 8];

    // gate identity: lanes 0..7 = local sorted pos within group
    const int gj = lane & 7;
    const int g_act = (lane < 8);
    const int p_sort = grp * 8 + gj;
    const int mylen = lens_s[p_sort];
    const int mybat = order_s[p_sort];
    float* houtF = hbuf + (size_t)mybat * TT * HID + u_glob;
    float* houtB = hbuf + (size_t)(BB + mybat) * TT * HID + u_glob;
    float* hpF = hping + (size_t)mybat * HID + u_glob;
    float* hpB = hping + (size_t)(BB + mybat) * HID + u_glob;

    // h staging: 4 slots/thread. kq = tid&127, rA = tid>>7 (0..3)
    const int kq = tid & 127;
    const int rA = tid >> 7;
    const int wbBase = 4 * kq + 4 * (kq >> 2);
    const int sb_lo = order_s[grp * 8 + rA];
    const int sb_hi = order_s[grp * 8 + rA + 4];

    // x staging: row16 = tid>>5 (0..15), part = tid&31 (8 floats each)
    const int xrow = tid >> 5;
    const int xpart = tid & 31;
    const int xjrow = xrow & 7;
    const int xlen = lens_s[grp * 8 + xjrow];
    const bool xisB = xrow >= 8;
    float* xdst = &xs[xrow * XSROW + xpart * 8];

    const int rdoff = 8 * lane + 4 * (lane >> 1);

    float cF = 0.f, cB = 0.f;
    unsigned* barF = bar + grp * 128;
    unsigned* barB = bar + (4 + grp) * 128;
    const int arr_line = (slice & 7) * 16;

#define DOTRED(WREG, WIH, ROWOFF, ZOFF)                                        \
    for (int j = 0; j < jmax; j++) {                                           \
        const float* hb = &hs[((ROWOFF) + j) * HSROW + rdoff];                 \
        float4 h0 = *(const float4*)(hb);                                      \
        float4 h1 = *(const float4*)(hb + 4);                                  \
        float4 xv = *(const float4*)&xs[((ROWOFF) + j) * XSROW + lane * 4];    \
        float a0 = 0.f, a1 = 0.f, a2 = 0.f, a3 = 0.f;                          \
        a0 = fmaf(WREG[0][0].x, h0.x, a0); a0 = fmaf(WREG[0][0].y, h0.y, a0);  \
        a0 = fmaf(WREG[0][0].z, h0.z, a0); a0 = fmaf(WREG[0][0].w, h0.w, a0);  \
        a0 = fmaf(WREG[0][1].x, h1.x, a0); a0 = fmaf(WREG[0][1].y, h1.y, a0);  \
        a0 = fmaf(WREG[0][1].z, h1.z, a0); a0 = fmaf(WREG[0][1].w, h1.w, a0);  \
        a0 = fmaf(WIH[0].x, xv.x, a0);     a0 = fmaf(WIH[0].y, xv.y, a0);      \
        a0 = fmaf(WIH[0].z, xv.z, a0);     a0 = fmaf(WIH[0].w, xv.w, a0);      \
        a1 = fmaf(WREG[1][0].x, h0.x, a1); a1 = fmaf(WREG[1][0].y, h0.y, a1);  \
        a1 = fmaf(WREG[1][0].z, h0.z, a1); a1 = fmaf(WREG[1][0].w, h0.w, a1);  \
        a1 = fmaf(WREG[1][1].x, h1.x, a1); a1 = fmaf(WREG[1][1].y, h1.y, a1);  \
        a1 = fmaf(WREG[1][1].z, h1.z, a1); a1 = fmaf(WREG[1][1].w, h1.w, a1);  \
        a1 = fmaf(WIH[1].x, xv.x, a1);     a1 = fmaf(WIH[1].y, xv.y, a1);      \
        a1 = fmaf(WIH[1].z, xv.z, a1);     a1 = fmaf(WIH[1].w, xv.w, a1);      \
        a2 = fmaf(WREG[2][0].x, h0.x, a2); a2 = fmaf(WREG[2][0].y, h0.y, a2);  \
        a2 = fmaf(WREG[2][0].z, h0.z, a2); a2 = fmaf(WREG[2][0].w, h0.w, a2);  \
        a2 = fmaf(WREG[2][1].x, h1.x, a2); a2 = fmaf(WREG[2][1].y, h1.y, a2);  \
        a2 = fmaf(WREG[2][1].z, h1.z, a2); a2 = fmaf(WREG[2][1].w, h1.w, a2);  \
        a2 = fmaf(WIH[2].x, xv.x, a2);     a2 = fmaf(WIH[2].y, xv.y, a2);      \
        a2 = fmaf(WIH[2].z, xv.z, a2);     a2 = fmaf(WIH[2].w, xv.w, a2);      \
        a3 = fmaf(WREG[3][0].x, h0.x, a3); a3 = fmaf(WREG[3][0].y, h0.y, a3);  \
        a3 = fmaf(WREG[3][0].z, h0.z, a3); a3 = fmaf(WREG[3][0].w, h0.w, a3);  \
        a3 = fmaf(WREG[3][1].x, h1.x, a3); a3 = fmaf(WREG[3][1].y, h1.y, a3);  \
        a3 = fmaf(WREG[3][1].z, h1.z, a3); a3 = fmaf(WREG[3][1].w, h1.w, a3);  \
        a3 = fmaf(WIH[3].x, xv.x, a3);     a3 = fmaf(WIH[3].y, xv.y, a3);      \
        a3 = fmaf(WIH[3].z, xv.z, a3);     a3 = fmaf(WIH[3].w, xv.w, a3);      \
        bool lo32 = (lane & 32) == 0;                                          \
        float tA = __shfl_xor(lo32 ? a2 : a0, 32);                             \
        float tB = __shfl_xor(lo32 ? a3 : a1, 32);                             \
        float rAq = (lo32 ? a0 : a2) + tA;                                     \
        float rBq = (lo32 ? a1 : a3) + tB;                                     \
        bool lo16 = (lane & 16) == 0;                                          \
        float tC = __shfl_xor(lo16 ? rBq : rAq, 16);                           \
        float r  = (lo16 ? rAq : rBq) + tC;                                    \
        r += __shfl_xor(r, 8);                                                 \
        r += __shfl_xor(r, 4);                                                 \
        r += __shfl_xor(r, 2);                                                 \
        r += __shfl_xor(r, 1);                                                 \
        if ((lane & 15) == 0)                                                  \
            zw[((ZOFF) + wave) * 132 + (lane >> 4) * 33 + j] = r;              \
    }

    for (int t = 0; t < tlimit; t++) {
        const int nbt = nbt_s[t];
        const int jmax = min(max(nbt - grp * 8, 0), 8);
        const int act = g_act && (t < mylen);
        const int pred_lo = (grp * 8 + rA < nbt);
        const int pred_hi = (grp * 8 + rA + 4 < nbt);

        // ---- prefetch x rows (barrier-independent) ----
        int posx = xisB ? ((t < xlen) ? xlen - 1 - t : t) : t;
        const float* xr = emb + (size_t)stok[xjrow][posx] * EMB + xpart * 8;
        float4 xa = *(const float4*)xr;
        float4 xb2 = *(const float4*)(xr + 4);

        // ---- combined barrier wait: F lines on lanes 0-7, B on 8-15 ----
        if (t > 0 && wave == 0) {
            const unsigned tgt = (unsigned)t * 8u;
            const unsigned* cp = (lane < 8) ? (barF + lane * 16)
                               : (lane < 16) ? (barB + (lane - 8) * 16)
                               : barF;
            bool mydone = (lane >= 16);
            while (true) {
                if (!mydone)
                    mydone = __hip_atomic_load(cp, __ATOMIC_RELAXED,
                                               __HIP_MEMORY_SCOPE_AGENT) >= tgt;
                if (__ballot(mydone) == ~0ull) break;
                __builtin_amdgcn_s_sleep(1);
            }
        }
        __syncthreads();

        // ---- stage h(t) for BOTH dirs: 4 sc1 dwordx4 loads, one vmcnt ----
        {
            const char* baseF = (const char*)hping + (size_t)((t & 1) * 2) * BB * HID * 4;
            const char* baseB = baseF + (size_t)BB * HID * 4;
            const char* fb = baseF + (tid & 63) * 16;
            const char* a0 = pred_lo ? baseF + sb_lo * 2048 + kq * 16 : fb;
            const char* a1 = pred_hi ? baseF + sb_hi * 2048 + kq * 16 : fb;
            const char* a2 = pred_lo ? baseB + sb_lo * 2048 + kq * 16 : fb;
            const char* a3 = pred_hi ? baseB + sb_hi * 2048 + kq * 16 : fb;
            float4 u0, u1, u2, u3;
            asm volatile(
                "global_load_dwordx4 %0, %4, off sc0 sc1\n\t"
                "global_load_dwordx4 %1, %5, off sc0 sc1\n\t"
                "global_load_dwordx4 %2, %6, off sc0 sc1\n\t"
                "global_load_dwordx4 %3, %7, off sc0 sc1\n\t"
                "s_waitcnt vmcnt(0)"
                : "=&v"(u0), "=&v"(u1), "=&v"(u2), "=&v"(u3)
                : "v"(a0), "v"(a1), "v"(a2), "v"(a3)
                : "memory");
            *(float4*)&hs[(rA     ) * HSROW + wbBase] = u0;
            *(float4*)&hs[(rA +  4) * HSROW + wbBase] = u1;
            *(float4*)&hs[(rA +  8) * HSROW + wbBase] = u2;
            *(float4*)&hs[(rA + 12) * HSROW + wbBase] = u3;
            *(float4*)xdst = xa;
            *(float4*)(xdst + 4) = xb2;
        }
        __syncthreads();

        // ---- dots: F then B (Whh.h + Wih.x fused) ----
        DOTRED(wF, iF, 0, 0);
        DOTRED(wB, iB, 8, 8);

        // ---- gates: both dirs; exchange (hping) stores only ----
        float hnF = 0.f, hnB = 0.f;
        if (act) {
            {
                float iv = zw[wave * 132 +  0 + gj] + bFc[0];
                float fv = zw[wave * 132 + 33 + gj] + bFc[1];
                float gv = zw[wave * 132 + 66 + gj] + bFc[2];
                float ov = zw[wave * 132 + 99 + gj] + bFc[3];
                float cn = sigmoidf_(fv) * cF + sigmoidf_(iv) * tanhf(gv);
                hnF = sigmoidf_(ov) * tanhf(cn);
                cF = cn;
                __hip_atomic_store(hpF + (size_t)(((t + 1) & 1) * 2) * BB * HID,
                                   hnF, __ATOMIC_RELAXED, __HIP_MEMORY_SCOPE_AGENT);
            }
            {
                float iv = zw[(8 + wave) * 132 +  0 + gj] + bBc[0];
                float fv = zw[(8 + wave) * 132 + 33 + gj] + bBc[1];
                float gv = zw[(8 + wave) * 132 + 66 + gj] + bBc[2];
                float ov = zw[(8 + wave) * 132 + 99 + gj] + bBc[3];
                float cn = sigmoidf_(fv) * cB + sigmoidf_(iv) * tanhf(gv);
                hnB = sigmoidf_(ov) * tanhf(cn);
                cB = cn;
                __hip_atomic_store(hpB + (size_t)(((t + 1) & 1) * 2) * BB * HID,
                                   hnB, __ATOMIC_RELAXED, __HIP_MEMORY_SCOPE_AGENT);
            }
        }

        // ---- drain (exchange stores only) + WG-level arrives ----
        __syncthreads();
        if (t < tlimit - 1) {
            if (tid == 0)
                __hip_atomic_fetch_add(barF + arr_line, 1u,
                                       __ATOMIC_RELAXED, __HIP_MEMORY_SCOPE_AGENT);
            if (tid == 1)
                __hip_atomic_fetch_add(barB + arr_line, 1u,
                                       __ATOMIC_RELAXED, __HIP_MEMORY_SCOPE_AGENT);
        }

        // ---- history stores AFTER arrive (latency hides in next wait) ----
        if (act) {
            houtF[(size_t)t * HID] = hnF;
            houtB[(size_t)t * HID] = hnB;
        }
    }
#undef DOTRED
}

// ---------------------------------------------------------------------------
// K3: feats — one wave per (b,t), all 64 lanes, LDS transpose-reduce.
// ---------------------------------------------------------------------------
__global__ __launch_bounds__(256) void k_feats(
    const int* __restrict__ lengths,
    const float* __restrict__ hbuf,  // [2][B][T][512]
    const float* __restrict__ Wout,  // [20][1024]
    const float* __restrict__ bout,  // [20]
    float* __restrict__ feats)       // [B][T][20]
{
    const int w = threadIdx.x >> 6;
    const int lane = threadIdx.x & 63;
    const int idx = blockIdx.x * 4 + w;
    const int b = idx >> 8, t = idx & 255;
    const int len = lengths[b];

    __shared__ float red[4][64][21];

    float acc[KTAGS];
    bool active = (t < len);
    if (active) {
        const int ofs = lane * 16;
        const float* src = (ofs < HID)
            ? hbuf + ((size_t)b * TT + t) * HID + ofs
            : hbuf + ((size_t)(BB + b) * TT + (len - 1 - t)) * HID + (ofs - HID);
        float x[16];
        #pragma unroll
        for (int q = 0; q < 4; q++) {
            float4 v = *(const float4*)(src + 4 * q);
            x[4 * q] = v.x; x[4 * q + 1] = v.y; x[4 * q + 2] = v.z; x[4 * q + 3] = v.w;
        }
        #pragma unroll
        for (int k = 0; k < KTAGS; k++) {
            const float* wr = Wout + (size_t)k * (2 * HID) + ofs;
            float a = 0.f;
            #pragma unroll
            for (int q = 0; q < 4; q++) {
                float4 v = *(const float4*)(wr + 4 * q);
                a = fmaf(x[4 * q], v.x, a);
                a = fmaf(x[4 * q + 1], v.y, a);
                a = fmaf(x[4 * q + 2], v.z, a);
                a = fmaf(x[4 * q + 3], v.w, a);
            }
            acc[k] = a;
        }
    } else {
        #pragma unroll
        for (int k = 0; k < KTAGS; k++) acc[k] = 0.f;
    }
    #pragma unroll
    for (int k = 0; k < KTAGS; k++) red[w][lane][k] = acc[k];
    __syncthreads();

    if (active && lane < KTAGS) {
        float s = bout[lane];
        #pragma unroll 8
        for (int l = 0; l < 64; l++) s += red[w][l][lane];
        feats[(size_t)idx * KTAGS + lane] = s;
    }
}

// ---------------------------------------------------------------------------
// K4: Viterbi — LDS backpointers, double-buffered fv, feats prefetch.
// ---------------------------------------------------------------------------
__global__ __launch_bounds__(64) void k_viterbi(
    const int* __restrict__ lengths,
    const float* __restrict__ trans,  // [20][20]
    const float* __restrict__ feats,  // [B][T][20]
    float* __restrict__ out)          // [32 scores][32*257 path]
{
    const int b = blockIdx.x;
    const int len = lengths[b];
    const int tid = threadIdx.x;

    __shared__ float tr[KTAGS * KTAGS];
    __shared__ float fvb[2][KTAGS];
    __shared__ int   bp[TT][KTAGS];
    __shared__ float term[KTAGS];

    for (int i = tid; i < KTAGS * KTAGS; i += 64) tr[i] = trans[i];
    if (tid < KTAGS) fvb[0][tid] = (tid == START_TAG) ? 0.f : NEGV;
    __syncthreads();

    float ft = (tid < KTAGS) ? feats[((size_t)b * TT) * KTAGS + tid] : 0.f;
    for (int t = 0; t < len; t++) {
        float ftn = (tid < KTAGS && t + 1 < len)
                  ? feats[((size_t)b * TT + t + 1) * KTAGS + tid] : 0.f;
        if (tid < KTAGS) {
            const float* fvc = fvb[t & 1];
            float best = -1e30f; int bi = 0;
            #pragma unroll
            for (int p = 0; p < KTAGS; p++) {
                float s = fvc[p] + tr[tid * KTAGS + p];
                if (s > best) { best = s; bi = p; }
            }
            fvb[(t + 1) & 1][tid] = best + ft;
            bp[t][tid] = bi;
        }
        ft = ftn;
        __syncthreads();
    }

    if (tid < KTAGS) term[tid] = fvb[len & 1][tid] + tr[END_TAG * KTAGS + tid];
    __syncthreads();

    if (tid == 0) {
        int bt_ = 0; float best = term[0];
        for (int k = 1; k < KTAGS; k++)
            if (term[k] > best) { best = term[k]; bt_ = k; }
        out[b] = best;
        float* path = out + BB + (size_t)b * (TT + 1);
        path[TT] = (float)bt_;
        int cur = bt_;
        for (int t = TT - 1; t >= 0; t--) {
            int src = t - (TT - len);
            if (src >= 0) cur = bp[src][cur];
            else          cur = KTAGS;
            path[t] = (float)cur;
        }
    }
}

// ---------------------------------------------------------------------------
extern "C" void kernel_launch(void* const* d_in, const int* in_sizes, int n_in,
                              void* d_out, int out_size, void* d_ws, size_t ws_size,
                              hipStream_t stream) {
    const int*   sentence = (const int*)d_in[0];
    const int*   lengths  = (const int*)d_in[1];
    const float* emb      = (const float*)d_in[2];
    const float* Wf_ih    = (const float*)d_in[3];
    const float* Wf_hh    = (const float*)d_in[4];
    const float* bf_ih    = (const float*)d_in[5];
    const float* bf_hh    = (const float*)d_in[6];
    const float* Wb_ih    = (const float*)d_in[7];
    const float* Wb_hh    = (const float*)d_in[8];
    const float* bb_ih    = (const float*)d_in[9];
    const float* bb_hh    = (const float*)d_in[10];
    const float* Wout     = (const float*)d_in[11];
    const float* bout     = (const float*)d_in[12];
    const float* trans    = (const float*)d_in[13];
    float* out = (float*)d_out;

    // workspace layout
    float*    hping = (float*)d_ws;                            // 65536 floats (256KB)
    unsigned* bar   = (unsigned*)((char*)d_ws + 65536 * 4);    // 4KB (8 cohorts x 8 lines)
    float*    hbuf  = (float*)((char*)d_ws + 65536 * 4 + 4096);// 2*32*256*512 floats
    float*    feats = hbuf + (size_t)2 * BB * TT * HID;        // 32*256*20

    (void)hipMemsetAsync(d_ws, 0, 65536 * 4 + 4096, stream);

    hipLaunchKernelGGL(k_lstm_persist, dim3(256), dim3(512), 0, stream,
                       lengths, sentence, emb, Wf_hh, Wb_hh, Wf_ih, Wb_ih,
                       bf_ih, bf_hh, bb_ih, bb_hh, hping, bar, hbuf);
    hipLaunchKernelGGL(k_feats, dim3(BB * TT / 4), dim3(256), 0, stream,
                       lengths, hbuf, Wout, bout, feats);
    hipLaunchKernelGGL(k_viterbi, dim3(BB), dim3(64), 0, stream,
                       lengths, trans, feats, out);
}